// Round 2
// baseline (311.305 us; speedup 1.0000x reference)
//
#include <hip/hip_runtime.h>
#include <stdint.h>

#define D_MODEL 1024
#define NHEAD   16
#define DKH     64
#define NB      2
#define SSEQ    2048

typedef unsigned short u16;
typedef __bf16 bf16x8 __attribute__((ext_vector_type(8)));
typedef float  f32x4  __attribute__((ext_vector_type(4)));
typedef u16    u16x8  __attribute__((ext_vector_type(8)));

__device__ __forceinline__ u16 f2bf(float x) {
  union { float f; uint32_t u; } c; c.f = x;
  uint32_t r = c.u + 0x7FFFu + ((c.u >> 16) & 1u);
  return (u16)(r >> 16);
}

__device__ __forceinline__ void gload_lds16(const void* gsrc, void* ldsdst) {
  typedef const __attribute__((address_space(1))) uint32_t* gp_t;
  typedef __attribute__((address_space(3))) uint32_t* lp_t;
  gp_t g = reinterpret_cast<gp_t>(reinterpret_cast<uintptr_t>(gsrc));
  lp_t l = reinterpret_cast<lp_t>(reinterpret_cast<uintptr_t>(ldsdst));
  __builtin_amdgcn_global_load_lds(g, l, 16, 0, 0);
}

__device__ __forceinline__ f32x4 mfma16(bf16x8 a, bf16x8 b, f32x4 c) {
  return __builtin_amdgcn_mfma_f32_16x16x32_bf16(a, b, c, 0, 0, 0);
}

// Tiles are [R][64] bf16 (128 B rows). XOR-8 swizzle on 16B chunks within a row.
__device__ __forceinline__ bf16x8 lds_frag(const u16* tile, int row, int kelem) {
  int chunk = (kelem >> 3) ^ (row & 7);
  return *reinterpret_cast<const bf16x8*>(
      reinterpret_cast<const char*>(tile) + row * 128 + chunk * 16);
}

template<int NROWS>
__device__ __forceinline__ void stage_tile(const u16* __restrict__ g, int row0, int ldk,
                                           int k0, u16* ldsbase, int wid, int lane) {
  constexpr int CPW = NROWS / 32;
  #pragma unroll
  for (int i = 0; i < CPW; ++i) {
    int c = wid * CPW + i;
    int row = c * 8 + (lane >> 3);
    int cchunk = (lane & 7) ^ (lane >> 3);
    const u16* src = g + (size_t)(row0 + row) * ldk + k0 + cchunk * 8;
    gload_lds16(src, reinterpret_cast<char*>(ldsbase) + c * 1024);
  }
}

// ---------------- cast f32 -> bf16 ----------------
__global__ __launch_bounds__(256) void cast_kernel(
    const float* __restrict__ s0, const float* __restrict__ s1,
    const float* __restrict__ s2, const float* __restrict__ s3,
    u16* __restrict__ d0, u16* __restrict__ d1, u16* __restrict__ d2, u16* __restrict__ d3,
    int n8) {
  const int z = blockIdx.z;
  const float* s = (z == 0) ? s0 : (z == 1) ? s1 : (z == 2) ? s2 : s3;
  u16* d = (z == 0) ? d0 : (z == 1) ? d1 : (z == 2) ? d2 : d3;
  int i = blockIdx.x * 256 + threadIdx.x;
  if (i >= n8) return;
  float4 a = reinterpret_cast<const float4*>(s)[2 * i];
  float4 b = reinterpret_cast<const float4*>(s)[2 * i + 1];
  u16x8 o;
  o[0] = f2bf(a.x); o[1] = f2bf(a.y); o[2] = f2bf(a.z); o[3] = f2bf(a.w);
  o[4] = f2bf(b.x); o[5] = f2bf(b.y); o[6] = f2bf(b.z); o[7] = f2bf(b.w);
  reinterpret_cast<u16x8*>(d)[i] = o;
}

// ---------------- shared 128x128 GEMM core (C = A @ W^T), K=1024 ----------------
__device__ __forceinline__ void gemm_core(const u16* __restrict__ A, const u16* __restrict__ W,
                                          u16* ldsA, u16* ldsB, int brow, int bcol,
                                          f32x4 acc[4][4]) {
  const int tid = threadIdx.x;
  const int lane = tid & 63;
  const int wid = tid >> 6;
  const int wr = wid >> 1;
  const int wc = wid & 1;
  f32x4 z4 = {0.f, 0.f, 0.f, 0.f};
  #pragma unroll
  for (int i = 0; i < 4; ++i)
    #pragma unroll
    for (int j = 0; j < 4; ++j) acc[i][j] = z4;

  stage_tile<128>(A, brow, D_MODEL, 0, ldsA, wid, lane);
  stage_tile<128>(W, bcol, D_MODEL, 0, ldsB, wid, lane);
  __syncthreads();
  int buf = 0;
  const int KT = D_MODEL / 64;
  for (int kt = 0; kt < KT; ++kt) {
    if (kt + 1 < KT) {
      stage_tile<128>(A, brow, D_MODEL, (kt + 1) * 64, ldsA + (buf ^ 1) * 8192, wid, lane);
      stage_tile<128>(W, bcol, D_MODEL, (kt + 1) * 64, ldsB + (buf ^ 1) * 8192, wid, lane);
    }
    const u16* tA = ldsA + buf * 8192;
    const u16* tB = ldsB + buf * 8192;
    #pragma unroll
    for (int kk = 0; kk < 2; ++kk) {
      const int ke = kk * 32 + ((lane >> 4) << 3);
      bf16x8 af[4], bf[4];
      #pragma unroll
      for (int i = 0; i < 4; ++i) af[i] = lds_frag(tA, wr * 64 + i * 16 + (lane & 15), ke);
      #pragma unroll
      for (int j = 0; j < 4; ++j) bf[j] = lds_frag(tB, wc * 64 + j * 16 + (lane & 15), ke);
      __builtin_amdgcn_s_setprio(1);
      #pragma unroll
      for (int i = 0; i < 4; ++i)
        #pragma unroll
        for (int j = 0; j < 4; ++j) acc[i][j] = mfma16(af[i], bf[j], acc[i][j]);
      __builtin_amdgcn_s_setprio(0);
    }
    __syncthreads();
    buf ^= 1;
  }
}

__global__ __launch_bounds__(256) void gemm_qkv(
    const u16* __restrict__ x0, const u16* __restrict__ x1, const u16* __restrict__ x2,
    const u16* __restrict__ w0, const u16* __restrict__ w1, const u16* __restrict__ w2,
    const float* __restrict__ b0, const float* __restrict__ b1, const float* __restrict__ b2,
    u16* __restrict__ o0, u16* __restrict__ o1, u16* __restrict__ o2) {
  __shared__ u16 ldsA[2 * 128 * 64];
  __shared__ u16 ldsB[2 * 128 * 64];
  const int z = blockIdx.z;
  const u16* X = (z == 0) ? x0 : (z == 1) ? x1 : x2;
  const u16* W = (z == 0) ? w0 : (z == 1) ? w1 : w2;
  const float* bias = (z == 0) ? b0 : (z == 1) ? b1 : b2;
  u16* O = (z == 0) ? o0 : (z == 1) ? o1 : o2;
  const float scale = (z == 0) ? 0.125f : 1.0f;
  const int brow = blockIdx.y * 128;
  const int bcol = blockIdx.x * 128;
  f32x4 acc[4][4];
  gemm_core(X, W, ldsA, ldsB, brow, bcol, acc);
  const int lane = threadIdx.x & 63;
  const int wid = threadIdx.x >> 6;
  const int wr = wid >> 1, wc = wid & 1;
  #pragma unroll
  for (int j = 0; j < 4; ++j) {
    const int n = bcol + wc * 64 + j * 16 + (lane & 15);
    const float bn = bias[n];
    const int h = n >> 6, d = n & 63;
    #pragma unroll
    for (int i = 0; i < 4; ++i)
      #pragma unroll
      for (int r = 0; r < 4; ++r) {
        const int m = brow + wr * 64 + i * 16 + ((lane >> 4) << 2) + r;
        const int bb = m >> 11, s = m & (SSEQ - 1);
        O[(((size_t)(bb * NHEAD + h) * SSEQ + s) << 6) + d] = f2bf((acc[i][j][r] + bn) * scale);
      }
  }
}

__global__ __launch_bounds__(256) void gemm_out(const u16* __restrict__ A,
                                                const u16* __restrict__ W,
                                                const float* __restrict__ bias,
                                                float* __restrict__ out) {
  __shared__ u16 ldsA[2 * 128 * 64];
  __shared__ u16 ldsB[2 * 128 * 64];
  const int brow = blockIdx.y * 128;
  const int bcol = blockIdx.x * 128;
  f32x4 acc[4][4];
  gemm_core(A, W, ldsA, ldsB, brow, bcol, acc);
  const int lane = threadIdx.x & 63;
  const int wid = threadIdx.x >> 6;
  const int wr = wid >> 1, wc = wid & 1;
  #pragma unroll
  for (int j = 0; j < 4; ++j) {
    const int n = bcol + wc * 64 + j * 16 + (lane & 15);
    const float bn = bias[n];
    #pragma unroll
    for (int i = 0; i < 4; ++i)
      #pragma unroll
      for (int r = 0; r < 4; ++r) {
        const int m = brow + wr * 64 + i * 16 + ((lane >> 4) << 2) + r;
        out[(size_t)m * D_MODEL + n] = acc[i][j][r] + bn;
      }
  }
}

// V [B,H,S,Dk] -> Vt [B,H,Dk,S]
__global__ __launch_bounds__(256) void transpose_v(const u16* __restrict__ V,
                                                   u16* __restrict__ Vt) {
  __shared__ u16 t[64][72];
  const int tid = threadIdx.x;
  const int bh = blockIdx.y;
  const int s0 = blockIdx.x * 64;
  const u16* Vb = V + ((size_t)bh * SSEQ + s0) * DKH;
  const int row = tid >> 2;
  const int cg = (tid & 3) * 16;
  uint4 a = *reinterpret_cast<const uint4*>(Vb + (size_t)row * DKH + cg);
  uint4 b = *reinterpret_cast<const uint4*>(Vb + (size_t)row * DKH + cg + 8);
  *reinterpret_cast<uint4*>(&t[row][cg]) = a;
  *reinterpret_cast<uint4*>(&t[row][cg + 8]) = b;
  __syncthreads();
  const int d = tid >> 2;
  const int sg = (tid & 3) * 16;
  u16 vals[16];
  #pragma unroll
  for (int j = 0; j < 16; ++j) vals[j] = t[sg + j][d];
  u16* dst = Vt + ((size_t)bh * DKH + d) * SSEQ + s0 + sg;
  *reinterpret_cast<uint4*>(dst) = *reinterpret_cast<uint4*>(&vals[0]);
  *reinterpret_cast<uint4*>(dst + 8) = *reinterpret_cast<uint4*>(&vals[8]);
}

// ---- Flash attention, barrier-free: 1 wave = one 16-row q-strip; K/V frags
// ---- read directly from global (L2-resident); strips paired for uniform work.
__device__ __forceinline__ void attn_strip(const u16* __restrict__ Qb,
                                           const u16* __restrict__ Kb,
                                           const u16* __restrict__ Vb,
                                           u16* __restrict__ ctxb,
                                           u16* myP, int strip, int lane) {
  const int g = lane >> 4;
  const int q0 = strip * 16;
  const int nt = (strip >> 2) + 1;  // tiles 0..strip>>2 (diag = last)
  const u16* Qp = Qb + (size_t)(q0 + (lane & 15)) * DKH + (g << 3);
  bf16x8 qf0 = *reinterpret_cast<const bf16x8*>(Qp);
  bf16x8 qf1 = *reinterpret_cast<const bf16x8*>(Qp + 32);

  f32x4 z4 = {0.f, 0.f, 0.f, 0.f};
  f32x4 acc[4] = {z4, z4, z4, z4};
  float mrow[4] = {-1e30f, -1e30f, -1e30f, -1e30f};
  float lrow[4] = {0.f, 0.f, 0.f, 0.f};

  bf16x8 kf[8], vf[8];
  // preload K tile 0
  #pragma unroll
  for (int jk = 0; jk < 4; ++jk)
    #pragma unroll
    for (int c = 0; c < 2; ++c)
      kf[jk * 2 + c] = *reinterpret_cast<const bf16x8*>(
          Kb + (size_t)(jk * 16 + (lane & 15)) * DKH + c * 32 + (g << 3));

  for (int t = 0; t < nt; ++t) {
    // V loads for tile t (consumed ~500 cyc later in PV)
    #pragma unroll
    for (int j = 0; j < 4; ++j)
      #pragma unroll
      for (int c = 0; c < 2; ++c)
        vf[j * 2 + c] = *reinterpret_cast<const bf16x8*>(
            Vb + (size_t)(j * 16 + (lane & 15)) * SSEQ + t * 64 + c * 32 + (g << 3));
    // QK^T
    f32x4 sf[4];
    __builtin_amdgcn_s_setprio(1);
    #pragma unroll
    for (int jk = 0; jk < 4; ++jk) {
      f32x4 s = mfma16(qf0, kf[jk * 2 + 0], z4);
      sf[jk] = mfma16(qf1, kf[jk * 2 + 1], s);
    }
    __builtin_amdgcn_s_setprio(0);
    // prefetch K tile t+1 (kf dead after QK)
    if (t + 1 < nt) {
      #pragma unroll
      for (int jk = 0; jk < 4; ++jk)
        #pragma unroll
        for (int c = 0; c < 2; ++c)
          kf[jk * 2 + c] = *reinterpret_cast<const bf16x8*>(
              Kb + (size_t)((t + 1) * 64 + jk * 16 + (lane & 15)) * DKH + c * 32 + (g << 3));
    }
    if (t == nt - 1) {  // diagonal tile: causal mask
      #pragma unroll
      for (int jk = 0; jk < 4; ++jk)
        #pragma unroll
        for (int r = 0; r < 4; ++r) {
          int kv = t * 64 + jk * 16 + (lane & 15);
          int qrow = q0 + g * 4 + r;
          if (kv > qrow) sf[jk][r] = -1e9f;
        }
    }
    // online softmax (row q = g*4+r spread across the 16 lanes of group g)
    float scl[4];
    #pragma unroll
    for (int r = 0; r < 4; ++r) {
      float mx = fmaxf(fmaxf(sf[0][r], sf[1][r]), fmaxf(sf[2][r], sf[3][r]));
      #pragma unroll
      for (int dd = 1; dd < 16; dd <<= 1) mx = fmaxf(mx, __shfl_xor(mx, dd));
      float mn = fmaxf(mrow[r], mx);
      scl[r] = __expf(mrow[r] - mn);
      mrow[r] = mn;
      lrow[r] *= scl[r];
    }
    float rsum[4] = {0.f, 0.f, 0.f, 0.f};
    #pragma unroll
    for (int jk = 0; jk < 4; ++jk)
      #pragma unroll
      for (int r = 0; r < 4; ++r) {
        float p = __expf(sf[jk][r] - mrow[r]);
        rsum[r] += p;
        int row = g * 4 + r;
        int col = jk * 16 + (lane & 15);
        int chunk = (col >> 3) ^ (row & 7);
        *reinterpret_cast<u16*>(reinterpret_cast<char*>(myP) + row * 128 + chunk * 16 +
                                (col & 7) * 2) = f2bf(p);
      }
    #pragma unroll
    for (int r = 0; r < 4; ++r) {
      float s = rsum[r];
      #pragma unroll
      for (int dd = 1; dd < 16; dd <<= 1) s += __shfl_xor(s, dd);
      lrow[r] += s;
    }
    #pragma unroll
    for (int j = 0; j < 4; ++j)
      #pragma unroll
      for (int r = 0; r < 4; ++r) acc[j][r] *= scl[r];
    // PV
    #pragma unroll
    for (int c = 0; c < 2; ++c) {
      bf16x8 pf = lds_frag(myP, lane & 15, c * 32 + (g << 3));
      __builtin_amdgcn_s_setprio(1);
      #pragma unroll
      for (int j = 0; j < 4; ++j) acc[j] = mfma16(pf, vf[j * 2 + c], acc[j]);
      __builtin_amdgcn_s_setprio(0);
    }
  }
  float inv[4];
  #pragma unroll
  for (int r = 0; r < 4; ++r) inv[r] = 1.0f / lrow[r];
  #pragma unroll
  for (int j = 0; j < 4; ++j)
    #pragma unroll
    for (int r = 0; r < 4; ++r) {
      int qrow = q0 + g * 4 + r;
      int d = j * 16 + (lane & 15);
      ctxb[(size_t)qrow * D_MODEL + d] = f2bf(acc[j][r] * inv[r]);
    }
}

__global__ __launch_bounds__(256) void attn_kernel(const u16* __restrict__ Q,
                                                   const u16* __restrict__ K,
                                                   const u16* __restrict__ Vt,
                                                   u16* __restrict__ ctx) {
  __shared__ u16 ldsP[4 * 16 * 64];
  const int lane = threadIdx.x & 63;
  const int wid = threadIdx.x >> 6;
  // XCD-aware remap: each XCD (blocks with L%8==xcd) serves 4 heads -> 2MB K/V in its L2
  const int L = blockIdx.x + 16 * blockIdx.y;  // 0..511
  const int bh = ((L & 7) << 2) | ((L >> 3) & 3);
  const int p = (((L >> 5) & 15) << 2) | wid;  // pair index 0..63
  const u16* Qb = Q + (size_t)bh * SSEQ * DKH;
  const u16* Kb = K + (size_t)bh * SSEQ * DKH;
  const u16* Vb = Vt + (size_t)bh * DKH * SSEQ;
  u16* ctxb = ctx + (size_t)(bh >> 4) * SSEQ * D_MODEL + (bh & 15) * DKH;
  u16* myP = ldsP + wid * 1024;
  attn_strip(Qb, Kb, Vb, ctxb, myP, 127 - p, lane);  // long strip first
  attn_strip(Qb, Kb, Vb, ctxb, myP, p, lane);
}

extern "C" void kernel_launch(void* const* d_in, const int* in_sizes, int n_in,
                              void* d_out, int out_size, void* d_ws, size_t ws_size,
                              hipStream_t stream) {
  const float* q  = (const float*)d_in[0];
  const float* k  = (const float*)d_in[1];
  const float* v  = (const float*)d_in[2];
  const float* Wq = (const float*)d_in[4];
  const float* bq = (const float*)d_in[5];
  const float* Wk = (const float*)d_in[6];
  const float* bk = (const float*)d_in[7];
  const float* Wv = (const float*)d_in[8];
  const float* bv = (const float*)d_in[9];
  const float* Wo = (const float*)d_in[10];
  const float* bo = (const float*)d_in[11];

  char* ws = (char*)d_ws;
  const size_t SZ_QKV = (size_t)NB * SSEQ * D_MODEL * 2;
  const size_t SZ_W   = (size_t)D_MODEL * D_MODEL * 2;
  u16* qb  = (u16*)(ws);
  u16* kb  = (u16*)(ws + SZ_QKV);
  u16* vb  = (u16*)(ws + 2 * SZ_QKV);
  u16* wqb = (u16*)(ws + 3 * SZ_QKV);
  u16* wkb = (u16*)(ws + 3 * SZ_QKV + SZ_W);
  u16* wvb = (u16*)(ws + 3 * SZ_QKV + 2 * SZ_W);
  u16* wob = (u16*)(ws + 3 * SZ_QKV + 3 * SZ_W);
  u16* Qh  = (u16*)(ws + 3 * SZ_QKV + 4 * SZ_W);
  u16* Kh  = (u16*)(ws + 4 * SZ_QKV + 4 * SZ_W);
  u16* Vh  = (u16*)(ws + 5 * SZ_QKV + 4 * SZ_W);
  u16* Vth = (u16*)(ws + 6 * SZ_QKV + 4 * SZ_W);
  u16* ctx = (u16*)(ws + 7 * SZ_QKV + 4 * SZ_W);

  cast_kernel<<<dim3(2048, 1, 3), 256, 0, stream>>>(
      q, k, v, nullptr, qb, kb, vb, nullptr, (NB * SSEQ * D_MODEL) / 8);
  cast_kernel<<<dim3(512, 1, 4), 256, 0, stream>>>(
      Wq, Wk, Wv, Wo, wqb, wkb, wvb, wob, (D_MODEL * D_MODEL) / 8);
  gemm_qkv<<<dim3(8, 32, 3), 256, 0, stream>>>(qb, kb, vb, wqb, wkb, wvb,
                                               bq, bk, bv, Qh, Kh, Vh);
  transpose_v<<<dim3(SSEQ / 64, NB * NHEAD), 256, 0, stream>>>(Vh, Vth);
  attn_kernel<<<dim3(16, 32), 256, 0, stream>>>(Qh, Kh, Vth, ctx);
  gemm_out<<<dim3(8, 32), 256, 0, stream>>>(ctx, wob, bo, (float*)d_out);
}

// Round 4
// 279.955 us; speedup vs baseline: 1.1120x; 1.1120x over previous
//
#include <hip/hip_runtime.h>
#include <stdint.h>

#define D_MODEL 1024
#define NHEAD   16
#define DKH     64
#define NB      2
#define SSEQ    2048

typedef unsigned short u16;
typedef __bf16 bf16x8 __attribute__((ext_vector_type(8)));
typedef float  f32x4  __attribute__((ext_vector_type(4)));
typedef float  f32x16 __attribute__((ext_vector_type(16)));
typedef u16    u16x8  __attribute__((ext_vector_type(8)));

__device__ __forceinline__ u16 f2bf(float x) {
  union { float f; uint32_t u; } c; c.f = x;
  uint32_t r = c.u + 0x7FFFu + ((c.u >> 16) & 1u);
  return (u16)(r >> 16);
}

__device__ __forceinline__ uint32_t cvtpk(float lo, float hi) {
  uint32_t r;
  asm("v_cvt_pk_bf16_f32 %0, %1, %2" : "=v"(r) : "v"(lo), "v"(hi));
  return r;
}

__device__ __forceinline__ void gload_lds16(const void* gsrc, void* ldsdst) {
  typedef const __attribute__((address_space(1))) uint32_t* gp_t;
  typedef __attribute__((address_space(3))) uint32_t* lp_t;
  gp_t g = reinterpret_cast<gp_t>(reinterpret_cast<uintptr_t>(gsrc));
  lp_t l = reinterpret_cast<lp_t>(reinterpret_cast<uintptr_t>(ldsdst));
  __builtin_amdgcn_global_load_lds(g, l, 16, 0, 0);
}

__device__ __forceinline__ f32x4 mfma16(bf16x8 a, bf16x8 b, f32x4 c) {
  return __builtin_amdgcn_mfma_f32_16x16x32_bf16(a, b, c, 0, 0, 0);
}
__device__ __forceinline__ f32x16 mfma32(bf16x8 a, bf16x8 b, f32x16 c) {
  return __builtin_amdgcn_mfma_f32_32x32x16_bf16(a, b, c, 0, 0, 0);
}

// [R][64] bf16 LDS tiles, XOR-8 swizzle on 16B chunks (GEMM path).
__device__ __forceinline__ bf16x8 lds_frag(const u16* tile, int row, int kelem) {
  int chunk = (kelem >> 3) ^ (row & 7);
  return *reinterpret_cast<const bf16x8*>(
      reinterpret_cast<const char*>(tile) + row * 128 + chunk * 16);
}

template<int NROWS>
__device__ __forceinline__ void stage_tile(const u16* __restrict__ g, int row0, int ldk,
                                           int k0, u16* ldsbase, int wid, int lane) {
  constexpr int CPW = NROWS / 32;
  #pragma unroll
  for (int i = 0; i < CPW; ++i) {
    int c = wid * CPW + i;
    int row = c * 8 + (lane >> 3);
    int cchunk = (lane & 7) ^ (lane >> 3);
    const u16* src = g + (size_t)(row0 + row) * ldk + k0 + cchunk * 8;
    gload_lds16(src, reinterpret_cast<char*>(ldsbase) + c * 1024);
  }
}

// ---------------- cast f32 -> bf16 ----------------
__global__ __launch_bounds__(256) void cast_kernel(
    const float* __restrict__ s0, const float* __restrict__ s1,
    const float* __restrict__ s2, const float* __restrict__ s3,
    u16* __restrict__ d0, u16* __restrict__ d1, u16* __restrict__ d2, u16* __restrict__ d3,
    int n8) {
  const int z = blockIdx.z;
  const float* s = (z == 0) ? s0 : (z == 1) ? s1 : (z == 2) ? s2 : s3;
  u16* d = (z == 0) ? d0 : (z == 1) ? d1 : (z == 2) ? d2 : d3;
  int i = blockIdx.x * 256 + threadIdx.x;
  if (i >= n8) return;
  float4 a = reinterpret_cast<const float4*>(s)[2 * i];
  float4 b = reinterpret_cast<const float4*>(s)[2 * i + 1];
  u16x8 o;
  o[0] = f2bf(a.x); o[1] = f2bf(a.y); o[2] = f2bf(a.z); o[3] = f2bf(a.w);
  o[4] = f2bf(b.x); o[5] = f2bf(b.y); o[6] = f2bf(b.z); o[7] = f2bf(b.w);
  reinterpret_cast<u16x8*>(d)[i] = o;
}

// ---------------- 128x128 GEMM core (C = A @ W^T), K=1024 ----------------
__device__ __forceinline__ void gemm_core(const u16* __restrict__ A, const u16* __restrict__ W,
                                          u16* ldsA, u16* ldsB, int brow, int bcol,
                                          f32x4 acc[4][4]) {
  const int tid = threadIdx.x;
  const int lane = tid & 63;
  const int wid = tid >> 6;
  const int wr = wid >> 1;
  const int wc = wid & 1;
  f32x4 z4 = {0.f, 0.f, 0.f, 0.f};
  #pragma unroll
  for (int i = 0; i < 4; ++i)
    #pragma unroll
    for (int j = 0; j < 4; ++j) acc[i][j] = z4;

  stage_tile<128>(A, brow, D_MODEL, 0, ldsA, wid, lane);
  stage_tile<128>(W, bcol, D_MODEL, 0, ldsB, wid, lane);
  __syncthreads();
  int buf = 0;
  const int KT = D_MODEL / 64;
  for (int kt = 0; kt < KT; ++kt) {
    if (kt + 1 < KT) {
      stage_tile<128>(A, brow, D_MODEL, (kt + 1) * 64, ldsA + (buf ^ 1) * 8192, wid, lane);
      stage_tile<128>(W, bcol, D_MODEL, (kt + 1) * 64, ldsB + (buf ^ 1) * 8192, wid, lane);
    }
    const u16* tA = ldsA + buf * 8192;
    const u16* tB = ldsB + buf * 8192;
    #pragma unroll
    for (int kk = 0; kk < 2; ++kk) {
      const int ke = kk * 32 + ((lane >> 4) << 3);
      bf16x8 af[4], bf[4];
      #pragma unroll
      for (int i = 0; i < 4; ++i) af[i] = lds_frag(tA, wr * 64 + i * 16 + (lane & 15), ke);
      #pragma unroll
      for (int j = 0; j < 4; ++j) bf[j] = lds_frag(tB, wc * 64 + j * 16 + (lane & 15), ke);
      __builtin_amdgcn_s_setprio(1);
      #pragma unroll
      for (int i = 0; i < 4; ++i)
        #pragma unroll
        for (int j = 0; j < 4; ++j) acc[i][j] = mfma16(af[i], bf[j], acc[i][j]);
      __builtin_amdgcn_s_setprio(0);
    }
    __syncthreads();
    buf ^= 1;
  }
}

__global__ __launch_bounds__(256) void gemm_qkv(
    const u16* __restrict__ x0, const u16* __restrict__ x1, const u16* __restrict__ x2,
    const u16* __restrict__ w0, const u16* __restrict__ w1, const u16* __restrict__ w2,
    const float* __restrict__ b0, const float* __restrict__ b1, const float* __restrict__ b2,
    u16* __restrict__ o0, u16* __restrict__ o1, u16* __restrict__ o2) {
  __shared__ u16 ldsA[2 * 128 * 64];
  __shared__ u16 ldsB[2 * 128 * 64];
  const int z = blockIdx.z;
  const u16* X = (z == 0) ? x0 : (z == 1) ? x1 : x2;
  const u16* W = (z == 0) ? w0 : (z == 1) ? w1 : w2;
  const float* bias = (z == 0) ? b0 : (z == 1) ? b1 : b2;
  u16* O = (z == 0) ? o0 : (z == 1) ? o1 : o2;
  const float scale = (z == 0) ? 0.125f : 1.0f;
  const int brow = blockIdx.y * 128;
  const int bcol = blockIdx.x * 128;
  f32x4 acc[4][4];
  gemm_core(X, W, ldsA, ldsB, brow, bcol, acc);
  const int lane = threadIdx.x & 63;
  const int wid = threadIdx.x >> 6;
  const int wr = wid >> 1, wc = wid & 1;
  #pragma unroll
  for (int j = 0; j < 4; ++j) {
    const int n = bcol + wc * 64 + j * 16 + (lane & 15);
    const float bn = bias[n];
    const int h = n >> 6, d = n & 63;
    #pragma unroll
    for (int i = 0; i < 4; ++i)
      #pragma unroll
      for (int r = 0; r < 4; ++r) {
        const int m = brow + wr * 64 + i * 16 + ((lane >> 4) << 2) + r;
        const int bb = m >> 11, s = m & (SSEQ - 1);
        O[(((size_t)(bb * NHEAD + h) * SSEQ + s) << 6) + d] = f2bf((acc[i][j][r] + bn) * scale);
      }
  }
}

__global__ __launch_bounds__(256) void gemm_out(const u16* __restrict__ A,
                                                const u16* __restrict__ W,
                                                const float* __restrict__ bias,
                                                float* __restrict__ out) {
  __shared__ u16 ldsA[2 * 128 * 64];
  __shared__ u16 ldsB[2 * 128 * 64];
  const int brow = blockIdx.y * 128;
  const int bcol = blockIdx.x * 128;
  f32x4 acc[4][4];
  gemm_core(A, W, ldsA, ldsB, brow, bcol, acc);
  const int lane = threadIdx.x & 63;
  const int wid = threadIdx.x >> 6;
  const int wr = wid >> 1, wc = wid & 1;
  #pragma unroll
  for (int j = 0; j < 4; ++j) {
    const int n = bcol + wc * 64 + j * 16 + (lane & 15);
    const float bn = bias[n];
    #pragma unroll
    for (int i = 0; i < 4; ++i)
      #pragma unroll
      for (int r = 0; r < 4; ++r) {
        const int m = brow + wr * 64 + i * 16 + ((lane >> 4) << 2) + r;
        out[(size_t)m * D_MODEL + n] = acc[i][j][r] + bn;
      }
  }
}

// V [B,H,S,Dk] -> Vt [B,H,Dk,S]
__global__ __launch_bounds__(256) void transpose_v(const u16* __restrict__ V,
                                                   u16* __restrict__ Vt) {
  __shared__ u16 t[64][72];
  const int tid = threadIdx.x;
  const int bh = blockIdx.y;
  const int s0 = blockIdx.x * 64;
  const u16* Vb = V + ((size_t)bh * SSEQ + s0) * DKH;
  const int row = tid >> 2;
  const int cg = (tid & 3) * 16;
  uint4 a = *reinterpret_cast<const uint4*>(Vb + (size_t)row * DKH + cg);
  uint4 b = *reinterpret_cast<const uint4*>(Vb + (size_t)row * DKH + cg + 8);
  *reinterpret_cast<uint4*>(&t[row][cg]) = a;
  *reinterpret_cast<uint4*>(&t[row][cg + 8]) = b;
  __syncthreads();
  const int d = tid >> 2;
  const int sg = (tid & 3) * 16;
  u16 vals[16];
  #pragma unroll
  for (int j = 0; j < 16; ++j) vals[j] = t[sg + j][d];
  u16* dst = Vt + ((size_t)bh * DKH + d) * SSEQ + s0 + sg;
  *reinterpret_cast<uint4*>(dst) = *reinterpret_cast<uint4*>(&vals[0]);
  *reinterpret_cast<uint4*>(dst + 8) = *reinterpret_cast<uint4*>(&vals[8]);
}

// ---- Flash attention, swapped-QK 32x32x16: S^T = mfma(K, Q) puts each q-row's
// ---- scores lane-local (row = lane&31 + partner lane^32). No LDS, no barriers.
union W4 { uint32_t w[4]; bf16x8 v; };

__device__ __forceinline__ void attn_strip32(const u16* __restrict__ Qb,
                                             const u16* __restrict__ Kb,
                                             const u16* __restrict__ Vb,
                                             u16* __restrict__ ctxb,
                                             int strip, int lane) {
  const int lo = lane & 31;
  const int hi = lane >> 5;
  const int q0 = strip * 32;
  const int nt = strip + 1;  // 32-kv tiles, diag = last

  // Q B-frags (held whole kernel): Q[q0+lo][slice*16 + hi*8 + 0..7]
  bf16x8 qf[4];
  const u16* qrow = Qb + (size_t)(q0 + lo) * DKH + hi * 8;
  #pragma unroll
  for (int s = 0; s < 4; ++s) qf[s] = *reinterpret_cast<const bf16x8*>(qrow + s * 16);

  // K A-frags tile 0: K[t*32+lo][slice*16 + hi*8 + ..]
  const u16* krow = Kb + (size_t)lo * DKH + hi * 8;
  bf16x8 kf[4];
  #pragma unroll
  for (int s = 0; s < 4; ++s) kf[s] = *reinterpret_cast<const bf16x8*>(krow + s * 16);

  // V B-frags tile 0: Vt[db*32+lo][t*32 + kh*16 + hi*8 + ..]
  const u16* vrow = Vb + (size_t)lo * SSEQ + hi * 8;
  bf16x8 vf[2][2];  // [kh][db]
  #pragma unroll
  for (int kh = 0; kh < 2; ++kh)
    #pragma unroll
    for (int db = 0; db < 2; ++db)
      vf[kh][db] = *reinterpret_cast<const bf16x8*>(vrow + db * 32 * SSEQ + kh * 16);

  f32x16 z16 = {};
  f32x16 acc0 = z16, acc1 = z16;
  float m = -1e30f, lsum = 0.f;

  for (int t = 0; t < nt; ++t) {
    // QK^T (swapped): sf[r] = S[q=lo][kv = t*32 + (r&3)+8*(r>>2)+4*hi]
    f32x16 sf = z16;
    __builtin_amdgcn_s_setprio(1);
    #pragma unroll
    for (int s = 0; s < 4; ++s) sf = mfma32(kf[s], qf[s], sf);
    __builtin_amdgcn_s_setprio(0);
    // prefetch K(t+1)
    if (t + 1 < nt) {
      const u16* kn = krow + (size_t)(t + 1) * 32 * DKH;
      #pragma unroll
      for (int s = 0; s < 4; ++s) kf[s] = *reinterpret_cast<const bf16x8*>(kn + s * 16);
    }
    if (t == nt - 1) {  // diagonal: mask kv > q (both local to tile/strip)
      #pragma unroll
      for (int r = 0; r < 16; ++r) {
        int kvp = (r & 3) + 8 * (r >> 2) + 4 * hi;
        if (kvp > lo) sf[r] = -1e9f;
      }
    }
    // row max: in-register tree + one cross-lane
    float t01 = fmaxf(sf[0], sf[1]),   t23 = fmaxf(sf[2], sf[3]);
    float t45 = fmaxf(sf[4], sf[5]),   t67 = fmaxf(sf[6], sf[7]);
    float t89 = fmaxf(sf[8], sf[9]),   tab = fmaxf(sf[10], sf[11]);
    float tcd = fmaxf(sf[12], sf[13]), tef = fmaxf(sf[14], sf[15]);
    float pm = fmaxf(fmaxf(fmaxf(t01, t23), fmaxf(t45, t67)),
                     fmaxf(fmaxf(t89, tab), fmaxf(tcd, tef)));
    pm = fmaxf(pm, __shfl_xor(pm, 32));
    if (t == 0) {
      m = pm;
    } else if (!__all(pm - m <= 6.0f)) {  // defer-max: rare rescale
      float mn = fmaxf(m, pm);
      float scl = __expf(m - mn);
      lsum *= scl;
      #pragma unroll
      for (int r = 0; r < 16; ++r) {
        int idx = (((r & 3) + 8 * (r >> 2)) << 2) + (hi << 4);
        float sr = __int_as_float(__builtin_amdgcn_ds_bpermute(idx, __float_as_int(scl)));
        acc0[r] *= sr;
        acc1[r] *= sr;
      }
      m = mn;
    }
    float pr[16];
    #pragma unroll
    for (int r = 0; r < 16; ++r) pr[r] = __expf(sf[r] - m);
    float rs = (((pr[0] + pr[1]) + (pr[2] + pr[3])) + ((pr[4] + pr[5]) + (pr[6] + pr[7]))) +
               (((pr[8] + pr[9]) + (pr[10] + pr[11])) + ((pr[12] + pr[13]) + (pr[14] + pr[15])));
    rs += __shfl_xor(rs, 32);
    lsum += rs;
    // pack P into PV A-frags (kv-slice0: pr0..7, slice1: pr8..15)
    uint32_t a = cvtpk(pr[0], pr[1]), b = cvtpk(pr[2], pr[3]);
    uint32_t c = cvtpk(pr[4], pr[5]), d = cvtpk(pr[6], pr[7]);
    uint32_t e = cvtpk(pr[8], pr[9]), f = cvtpk(pr[10], pr[11]);
    uint32_t g = cvtpk(pr[12], pr[13]), h = cvtpk(pr[14], pr[15]);
    uint32_t ap = __shfl_xor((int)a, 32), bp = __shfl_xor((int)b, 32);
    uint32_t cp = __shfl_xor((int)c, 32), dp = __shfl_xor((int)d, 32);
    uint32_t ep = __shfl_xor((int)e, 32), fp = __shfl_xor((int)f, 32);
    uint32_t gp = __shfl_xor((int)g, 32), hp = __shfl_xor((int)h, 32);
    W4 pa0, pa1;
    pa0.w[0] = hi ? cp : a;  pa0.w[1] = hi ? dp : b;
    pa0.w[2] = hi ? c : ap;  pa0.w[3] = hi ? d : bp;
    pa1.w[0] = hi ? gp : e;  pa1.w[1] = hi ? hp : f;
    pa1.w[2] = hi ? g : ep;  pa1.w[3] = hi ? h : fp;
    // PV
    __builtin_amdgcn_s_setprio(1);
    acc0 = mfma32(pa0.v, vf[0][0], acc0);
    acc0 = mfma32(pa1.v, vf[1][0], acc0);
    acc1 = mfma32(pa0.v, vf[0][1], acc1);
    acc1 = mfma32(pa1.v, vf[1][1], acc1);
    __builtin_amdgcn_s_setprio(0);
    // prefetch V(t+1)
    if (t + 1 < nt) {
      const u16* vn = vrow + (t + 1) * 32;
      #pragma unroll
      for (int kh = 0; kh < 2; ++kh)
        #pragma unroll
        for (int db = 0; db < 2; ++db)
          vf[kh][db] = *reinterpret_cast<const bf16x8*>(vn + db * 32 * SSEQ + kh * 16);
    }
  }
  float inv = 1.0f / lsum;
  #pragma unroll
  for (int r = 0; r < 16; ++r) {
    int rp = (r & 3) + 8 * (r >> 2) + 4 * hi;
    int idx = (((r & 3) + 8 * (r >> 2)) << 2) + (hi << 4);
    float ir = __int_as_float(__builtin_amdgcn_ds_bpermute(idx, __float_as_int(inv)));
    u16* orow = ctxb + (size_t)(q0 + rp) * D_MODEL;
    orow[lo] = f2bf(acc0[r] * ir);
    orow[32 + lo] = f2bf(acc1[r] * ir);
  }
}

__global__ __launch_bounds__(64) void attn_kernel(const u16* __restrict__ Q,
                                                  const u16* __restrict__ K,
                                                  const u16* __restrict__ Vt,
                                                  u16* __restrict__ ctx) {
  const int lane = threadIdx.x;
  const int bid = blockIdx.x;          // 0..2047, XCD = bid%8 (perf heuristic)
  const int j = bid >> 3;              // 0..255
  const int bh = ((bid & 7) << 2) | (j >> 6);  // 4 heads per XCD group
  const int strip = 63 - (j & 63);     // longest strips dispatch first
  const u16* Qb = Q + (size_t)bh * SSEQ * DKH;
  const u16* Kb = K + (size_t)bh * SSEQ * DKH;
  const u16* Vb = Vt + (size_t)bh * DKH * SSEQ;
  u16* ctxb = ctx + (size_t)(bh >> 4) * SSEQ * D_MODEL + (bh & 15) * DKH;
  attn_strip32(Qb, Kb, Vb, ctxb, strip, lane);
}

extern "C" void kernel_launch(void* const* d_in, const int* in_sizes, int n_in,
                              void* d_out, int out_size, void* d_ws, size_t ws_size,
                              hipStream_t stream) {
  const float* q  = (const float*)d_in[0];
  const float* k  = (const float*)d_in[1];
  const float* v  = (const float*)d_in[2];
  const float* Wq = (const float*)d_in[4];
  const float* bq = (const float*)d_in[5];
  const float* Wk = (const float*)d_in[6];
  const float* bk = (const float*)d_in[7];
  const float* Wv = (const float*)d_in[8];
  const float* bv = (const float*)d_in[9];
  const float* Wo = (const float*)d_in[10];
  const float* bo = (const float*)d_in[11];

  char* ws = (char*)d_ws;
  const size_t SZ_QKV = (size_t)NB * SSEQ * D_MODEL * 2;
  const size_t SZ_W   = (size_t)D_MODEL * D_MODEL * 2;
  u16* qb  = (u16*)(ws);
  u16* kb  = (u16*)(ws + SZ_QKV);
  u16* vb  = (u16*)(ws + 2 * SZ_QKV);
  u16* wqb = (u16*)(ws + 3 * SZ_QKV);
  u16* wkb = (u16*)(ws + 3 * SZ_QKV + SZ_W);
  u16* wvb = (u16*)(ws + 3 * SZ_QKV + 2 * SZ_W);
  u16* wob = (u16*)(ws + 3 * SZ_QKV + 3 * SZ_W);
  u16* Qh  = (u16*)(ws + 3 * SZ_QKV + 4 * SZ_W);
  u16* Kh  = (u16*)(ws + 4 * SZ_QKV + 4 * SZ_W);
  u16* Vh  = (u16*)(ws + 5 * SZ_QKV + 4 * SZ_W);
  u16* Vth = (u16*)(ws + 6 * SZ_QKV + 4 * SZ_W);
  u16* ctx = (u16*)(ws + 7 * SZ_QKV + 4 * SZ_W);

  cast_kernel<<<dim3(2048, 1, 3), 256, 0, stream>>>(
      q, k, v, nullptr, qb, kb, vb, nullptr, (NB * SSEQ * D_MODEL) / 8);
  cast_kernel<<<dim3(512, 1, 4), 256, 0, stream>>>(
      Wq, Wk, Wv, Wo, wqb, wkb, wvb, wob, (D_MODEL * D_MODEL) / 8);
  gemm_qkv<<<dim3(8, 32, 3), 256, 0, stream>>>(qb, kb, vb, wqb, wkb, wvb,
                                               bq, bk, bv, Qh, Kh, Vh);
  transpose_v<<<dim3(SSEQ / 64, NB * NHEAD), 256, 0, stream>>>(Vh, Vth);
  attn_kernel<<<dim3(2048), 64, 0, stream>>>(Qh, Kh, Vth, ctx);
  gemm_out<<<dim3(8, 32), 256, 0, stream>>>(ctx, wob, bo, (float*)d_out);
}

// Round 6
// 260.132 us; speedup vs baseline: 1.1967x; 1.0762x over previous
//
#include <hip/hip_runtime.h>
#include <stdint.h>

#define D_MODEL 1024
#define NHEAD   16
#define DKH     64
#define NB      2
#define SSEQ    2048

typedef unsigned short u16;
typedef __bf16 bf16x8 __attribute__((ext_vector_type(8)));
typedef float  f32x4  __attribute__((ext_vector_type(4)));
typedef float  f32x16 __attribute__((ext_vector_type(16)));
typedef u16    u16x8  __attribute__((ext_vector_type(8)));

__device__ __forceinline__ u16 f2bf(float x) {
  union { float f; uint32_t u; } c; c.f = x;
  uint32_t r = c.u + 0x7FFFu + ((c.u >> 16) & 1u);
  return (u16)(r >> 16);
}

__device__ __forceinline__ uint32_t cvtpk(float lo, float hi) {
  uint32_t r;
  asm("v_cvt_pk_bf16_f32 %0, %1, %2" : "=v"(r) : "v"(lo), "v"(hi));
  return r;
}

__device__ __forceinline__ void gload_lds16(const void* gsrc, void* ldsdst) {
  typedef const __attribute__((address_space(1))) uint32_t* gp_t;
  typedef __attribute__((address_space(3))) uint32_t* lp_t;
  gp_t g = reinterpret_cast<gp_t>(reinterpret_cast<uintptr_t>(gsrc));
  lp_t l = reinterpret_cast<lp_t>(reinterpret_cast<uintptr_t>(ldsdst));
  __builtin_amdgcn_global_load_lds(g, l, 16, 0, 0);
}

__device__ __forceinline__ f32x4 mfma16(bf16x8 a, bf16x8 b, f32x4 c) {
  return __builtin_amdgcn_mfma_f32_16x16x32_bf16(a, b, c, 0, 0, 0);
}
__device__ __forceinline__ f32x16 mfma32(bf16x8 a, bf16x8 b, f32x16 c) {
  return __builtin_amdgcn_mfma_f32_32x32x16_bf16(a, b, c, 0, 0, 0);
}

// [R][64] bf16 LDS tiles, XOR-8 swizzle on 16B chunks (GEMM path).
__device__ __forceinline__ bf16x8 lds_frag(const u16* tile, int row, int kelem) {
  int chunk = (kelem >> 3) ^ (row & 7);
  return *reinterpret_cast<const bf16x8*>(
      reinterpret_cast<const char*>(tile) + row * 128 + chunk * 16);
}

template<int NROWS>
__device__ __forceinline__ void stage_tile(const u16* __restrict__ g, int row0, int ldk,
                                           int k0, u16* ldsbase, int wid, int lane) {
  constexpr int CPW = NROWS / 32;
  #pragma unroll
  for (int i = 0; i < CPW; ++i) {
    int c = wid * CPW + i;
    int row = c * 8 + (lane >> 3);
    int cchunk = (lane & 7) ^ (lane >> 3);
    const u16* src = g + (size_t)(row0 + row) * ldk + k0 + cchunk * 8;
    gload_lds16(src, reinterpret_cast<char*>(ldsbase) + c * 1024);
  }
}

// ---------------- cast f32 -> bf16 ----------------
__global__ __launch_bounds__(256) void cast_kernel(
    const float* __restrict__ s0, const float* __restrict__ s1,
    const float* __restrict__ s2, const float* __restrict__ s3,
    u16* __restrict__ d0, u16* __restrict__ d1, u16* __restrict__ d2, u16* __restrict__ d3,
    int n8) {
  const int z = blockIdx.z;
  const float* s = (z == 0) ? s0 : (z == 1) ? s1 : (z == 2) ? s2 : s3;
  u16* d = (z == 0) ? d0 : (z == 1) ? d1 : (z == 2) ? d2 : d3;
  int i = blockIdx.x * 256 + threadIdx.x;
  if (i >= n8) return;
  float4 a = reinterpret_cast<const float4*>(s)[2 * i];
  float4 b = reinterpret_cast<const float4*>(s)[2 * i + 1];
  u16x8 o;
  o[0] = f2bf(a.x); o[1] = f2bf(a.y); o[2] = f2bf(a.z); o[3] = f2bf(a.w);
  o[4] = f2bf(b.x); o[5] = f2bf(b.y); o[6] = f2bf(b.z); o[7] = f2bf(b.w);
  reinterpret_cast<u16x8*>(d)[i] = o;
}

// ---------------- 128x128 GEMM core (C = A @ W^T), K=1024 ----------------
__device__ __forceinline__ void gemm_core(const u16* __restrict__ A, const u16* __restrict__ W,
                                          u16* ldsA, u16* ldsB, int brow, int bcol,
                                          f32x4 acc[4][4]) {
  const int tid = threadIdx.x;
  const int lane = tid & 63;
  const int wid = tid >> 6;
  const int wr = wid >> 1;
  const int wc = wid & 1;
  f32x4 z4 = {0.f, 0.f, 0.f, 0.f};
  #pragma unroll
  for (int i = 0; i < 4; ++i)
    #pragma unroll
    for (int j = 0; j < 4; ++j) acc[i][j] = z4;

  stage_tile<128>(A, brow, D_MODEL, 0, ldsA, wid, lane);
  stage_tile<128>(W, bcol, D_MODEL, 0, ldsB, wid, lane);
  __syncthreads();
  int buf = 0;
  const int KT = D_MODEL / 64;
  for (int kt = 0; kt < KT; ++kt) {
    if (kt + 1 < KT) {
      stage_tile<128>(A, brow, D_MODEL, (kt + 1) * 64, ldsA + (buf ^ 1) * 8192, wid, lane);
      stage_tile<128>(W, bcol, D_MODEL, (kt + 1) * 64, ldsB + (buf ^ 1) * 8192, wid, lane);
    }
    const u16* tA = ldsA + buf * 8192;
    const u16* tB = ldsB + buf * 8192;
    #pragma unroll
    for (int kk = 0; kk < 2; ++kk) {
      const int ke = kk * 32 + ((lane >> 4) << 3);
      bf16x8 af[4], bf[4];
      #pragma unroll
      for (int i = 0; i < 4; ++i) af[i] = lds_frag(tA, wr * 64 + i * 16 + (lane & 15), ke);
      #pragma unroll
      for (int j = 0; j < 4; ++j) bf[j] = lds_frag(tB, wc * 64 + j * 16 + (lane & 15), ke);
      __builtin_amdgcn_s_setprio(1);
      #pragma unroll
      for (int i = 0; i < 4; ++i)
        #pragma unroll
        for (int j = 0; j < 4; ++j) acc[i][j] = mfma16(af[i], bf[j], acc[i][j]);
      __builtin_amdgcn_s_setprio(0);
    }
    __syncthreads();
    buf ^= 1;
  }
}

__global__ __launch_bounds__(256) void gemm_qkv(
    const u16* __restrict__ x0, const u16* __restrict__ x1, const u16* __restrict__ x2,
    const u16* __restrict__ w0, const u16* __restrict__ w1, const u16* __restrict__ w2,
    const float* __restrict__ b0, const float* __restrict__ b1, const float* __restrict__ b2,
    u16* __restrict__ o0, u16* __restrict__ o1, u16* __restrict__ o2) {
  __shared__ u16 ldsA[2 * 128 * 64];
  __shared__ u16 ldsB[2 * 128 * 64];
  const int z = blockIdx.z;
  const u16* X = (z == 0) ? x0 : (z == 1) ? x1 : x2;
  const u16* W = (z == 0) ? w0 : (z == 1) ? w1 : w2;
  const float* bias = (z == 0) ? b0 : (z == 1) ? b1 : b2;
  u16* O = (z == 0) ? o0 : (z == 1) ? o1 : o2;
  const float scale = (z == 0) ? 0.125f : 1.0f;
  const int brow = blockIdx.y * 128;
  const int bcol = blockIdx.x * 128;
  f32x4 acc[4][4];
  gemm_core(X, W, ldsA, ldsB, brow, bcol, acc);
  const int lane = threadIdx.x & 63;
  const int wid = threadIdx.x >> 6;
  const int wr = wid >> 1, wc = wid & 1;
  #pragma unroll
  for (int j = 0; j < 4; ++j) {
    const int n = bcol + wc * 64 + j * 16 + (lane & 15);
    const float bn = bias[n];
    const int h = n >> 6, d = n & 63;
    #pragma unroll
    for (int i = 0; i < 4; ++i)
      #pragma unroll
      for (int r = 0; r < 4; ++r) {
        const int m = brow + wr * 64 + i * 16 + ((lane >> 4) << 2) + r;
        const int bb = m >> 11, s = m & (SSEQ - 1);
        O[(((size_t)(bb * NHEAD + h) * SSEQ + s) << 6) + d] = f2bf((acc[i][j][r] + bn) * scale);
      }
  }
}

__global__ __launch_bounds__(256) void gemm_out(const u16* __restrict__ A,
                                                const u16* __restrict__ W,
                                                const float* __restrict__ bias,
                                                float* __restrict__ out) {
  __shared__ u16 ldsA[2 * 128 * 64];
  __shared__ u16 ldsB[2 * 128 * 64];
  const int brow = blockIdx.y * 128;
  const int bcol = blockIdx.x * 128;
  f32x4 acc[4][4];
  gemm_core(A, W, ldsA, ldsB, brow, bcol, acc);
  const int lane = threadIdx.x & 63;
  const int wid = threadIdx.x >> 6;
  const int wr = wid >> 1, wc = wid & 1;
  #pragma unroll
  for (int j = 0; j < 4; ++j) {
    const int n = bcol + wc * 64 + j * 16 + (lane & 15);
    const float bn = bias[n];
    #pragma unroll
    for (int i = 0; i < 4; ++i)
      #pragma unroll
      for (int r = 0; r < 4; ++r) {
        const int m = brow + wr * 64 + i * 16 + ((lane >> 4) << 2) + r;
        out[(size_t)m * D_MODEL + n] = acc[i][j][r] + bn;
      }
  }
}

// V [B,H,S,Dk] -> Vt [B,H,Dk,S]
__global__ __launch_bounds__(256) void transpose_v(const u16* __restrict__ V,
                                                   u16* __restrict__ Vt) {
  __shared__ u16 t[64][72];
  const int tid = threadIdx.x;
  const int bh = blockIdx.y;
  const int s0 = blockIdx.x * 64;
  const u16* Vb = V + ((size_t)bh * SSEQ + s0) * DKH;
  const int row = tid >> 2;
  const int cg = (tid & 3) * 16;
  uint4 a = *reinterpret_cast<const uint4*>(Vb + (size_t)row * DKH + cg);
  uint4 b = *reinterpret_cast<const uint4*>(Vb + (size_t)row * DKH + cg + 8);
  *reinterpret_cast<uint4*>(&t[row][cg]) = a;
  *reinterpret_cast<uint4*>(&t[row][cg + 8]) = b;
  __syncthreads();
  const int d = tid >> 2;
  const int sg = (tid & 3) * 16;
  u16 vals[16];
  #pragma unroll
  for (int j = 0; j < 16; ++j) vals[j] = t[sg + j][d];
  u16* dst = Vt + ((size_t)bh * DKH + d) * SSEQ + s0 + sg;
  *reinterpret_cast<uint4*>(dst) = *reinterpret_cast<uint4*>(&vals[0]);
  *reinterpret_cast<uint4*>(dst + 8) = *reinterpret_cast<uint4*>(&vals[8]);
}

// ---- Flash attention: swapped-QK 32x32x16, per-wave LDS double-buffer staging
// ---- via global_load_lds (no barriers; vmcnt-counted). P-pack: verified
// ---- shfl_xor+cndmask path (R4). permlane32_swap retry deferred (direction TBD).
__device__ __forceinline__ void stage_kv(const u16* __restrict__ Kb,
                                         const u16* __restrict__ Vb,
                                         int t, char* kbuf, char* vbuf, int lane) {
  // K tile: 32 rows x 64 elems (128B rows, 8 chunks), XOR-8 pre-swizzled source.
  const u16* ks = Kb + (size_t)t * 32 * DKH;
  const int krow = lane >> 3;                 // row&7 within 8-row group
  const int kchunk = (lane & 7) ^ krow;
  #pragma unroll
  for (int i = 0; i < 4; ++i)
    gload_lds16(ks + (size_t)(i * 8 + krow) * DKH + kchunk * 8, kbuf + i * 1024);
  // V tile: 64 d-rows x 32 elems (64B rows, 4 chunks), +row>>1 rotated source.
  const int vr = lane >> 2;
  #pragma unroll
  for (int i = 0; i < 4; ++i) {
    int vrow = i * 16 + vr;
    int csrc = ((lane & 3) - (vrow >> 1)) & 3;
    gload_lds16(Vb + (size_t)vrow * SSEQ + t * 32 + csrc * 8, vbuf + i * 1024);
  }
}

__device__ __forceinline__ void attn_strip32(const u16* __restrict__ Qb,
                                             const u16* __restrict__ Kb,
                                             const u16* __restrict__ Vb,
                                             u16* __restrict__ ctxb,
                                             char* lds, int strip, int lane) {
  const int lo = lane & 31;
  const int hi = lane >> 5;
  const int q0 = strip * 32;
  const int nt = strip + 1;

  // Q B-frags (held whole kernel): Q[q0+lo][s*16 + hi*8 + 0..7]
  bf16x8 qf[4];
  const u16* qrow = Qb + (size_t)(q0 + lo) * DKH + hi * 8;
  #pragma unroll
  for (int s = 0; s < 4; ++s) qf[s] = *reinterpret_cast<const bf16x8*>(qrow + s * 16);
  asm volatile("s_waitcnt vmcnt(0)" ::: "memory");  // clean counter before staging
  __builtin_amdgcn_sched_barrier(0);

  stage_kv(Kb, Vb, 0, lds, lds + 4096, lane);       // tile 0 -> buf 0

  f32x16 z16 = {};
  f32x16 acc0 = z16, acc1 = z16;
  float m = -1e30f, lsum = 0.f;

  for (int t = 0; t < nt; ++t) {
    char* kb_l = lds + (t & 1) * 8192;
    char* vb_l = kb_l + 4096;
    if (t + 1 < nt) {
      stage_kv(Kb, Vb, t + 1, lds + ((t + 1) & 1) * 8192, lds + ((t + 1) & 1) * 8192 + 4096, lane);
      asm volatile("s_waitcnt vmcnt(8)" ::: "memory");   // tile t resident
    } else {
      asm volatile("s_waitcnt vmcnt(0)" ::: "memory");
    }
    __builtin_amdgcn_sched_barrier(0);

    // K A-frags from LDS (XOR-8 swizzle)
    bf16x8 kf[4];
    #pragma unroll
    for (int s = 0; s < 4; ++s)
      kf[s] = *reinterpret_cast<const bf16x8*>(kb_l + lo * 128 + ((((s << 1) | hi) ^ (lo & 7)) << 4));

    // QK^T (swapped): sf[r] = S[q=lo][kv = t*32 + (r&3)+8*(r>>2)+4*hi]
    f32x16 sf = z16;
    __builtin_amdgcn_s_setprio(1);
    #pragma unroll
    for (int s = 0; s < 4; ++s) sf = mfma32(kf[s], qf[s], sf);
    __builtin_amdgcn_s_setprio(0);

    if (t == nt - 1) {  // diagonal: mask kv > q
      #pragma unroll
      for (int r = 0; r < 16; ++r) {
        int kvp = (r & 3) + 8 * (r >> 2) + 4 * hi;
        if (kvp > lo) sf[r] = -1e9f;
      }
    }
    // half-row max (no cross-lane in common path)
    float t01 = fmaxf(sf[0], sf[1]),   t23 = fmaxf(sf[2], sf[3]);
    float t45 = fmaxf(sf[4], sf[5]),   t67 = fmaxf(sf[6], sf[7]);
    float t89 = fmaxf(sf[8], sf[9]),   tab = fmaxf(sf[10], sf[11]);
    float tcd = fmaxf(sf[12], sf[13]), tef = fmaxf(sf[14], sf[15]);
    float pm = fmaxf(fmaxf(fmaxf(t01, t23), fmaxf(t45, t67)),
                     fmaxf(fmaxf(t89, tab), fmaxf(tcd, tef)));
    if (t == 0) {
      m = fmaxf(pm, __shfl_xor(pm, 32));
    } else if (!__all(pm - m <= 6.0f)) {  // defer-max: rare rescale
      float mn = fmaxf(fmaxf(pm, __shfl_xor(pm, 32)), m);
      float scl = __expf(m - mn);
      lsum *= scl;
      #pragma unroll
      for (int r = 0; r < 16; ++r) {
        int idx = (((r & 3) + 8 * (r >> 2)) << 2) + (hi << 4);
        float sr = __int_as_float(__builtin_amdgcn_ds_bpermute(idx, __float_as_int(scl)));
        acc0[r] *= sr;
        acc1[r] *= sr;
      }
      m = mn;
    }
    float pr[16];
    #pragma unroll
    for (int r = 0; r < 16; ++r) pr[r] = __expf(sf[r] - m);
    float rs = (((pr[0] + pr[1]) + (pr[2] + pr[3])) + ((pr[4] + pr[5]) + (pr[6] + pr[7]))) +
               (((pr[8] + pr[9]) + (pr[10] + pr[11])) + ((pr[12] + pr[13]) + (pr[14] + pr[15])));
    lsum += rs;  // own-half only; combined once after the loop

    // pack P into PV A-frags: verified shfl_xor + cndmask path (R4)
    uint32_t a = cvtpk(pr[0], pr[1]), b = cvtpk(pr[2], pr[3]);
    uint32_t c = cvtpk(pr[4], pr[5]), d = cvtpk(pr[6], pr[7]);
    uint32_t e = cvtpk(pr[8], pr[9]), f = cvtpk(pr[10], pr[11]);
    uint32_t g = cvtpk(pr[12], pr[13]), h = cvtpk(pr[14], pr[15]);
    uint32_t ap = __shfl_xor((int)a, 32), bp = __shfl_xor((int)b, 32);
    uint32_t cp = __shfl_xor((int)c, 32), dp = __shfl_xor((int)d, 32);
    uint32_t ep = __shfl_xor((int)e, 32), fp = __shfl_xor((int)f, 32);
    uint32_t gp = __shfl_xor((int)g, 32), hp = __shfl_xor((int)h, 32);
    union W4 { uint32_t w[4]; bf16x8 v; } pa0, pa1;
    pa0.w[0] = hi ? cp : a;  pa0.w[1] = hi ? dp : b;
    pa0.w[2] = hi ? c : ap;  pa0.w[3] = hi ? d : bp;
    pa1.w[0] = hi ? gp : e;  pa1.w[1] = hi ? hp : f;
    pa1.w[2] = hi ? g : ep;  pa1.w[3] = hi ? h : fp;

    // V B-frags from LDS (+row>>1 rotation)
    bf16x8 vf[2][2];  // [kh][db]
    #pragma unroll
    for (int kh = 0; kh < 2; ++kh)
      #pragma unroll
      for (int db = 0; db < 2; ++db) {
        int row = db * 32 + lo;
        int cc = (((kh << 1) | hi) + (row >> 1)) & 3;
        vf[kh][db] = *reinterpret_cast<const bf16x8*>(vb_l + row * 64 + (cc << 4));
      }
    __builtin_amdgcn_s_setprio(1);
    acc0 = mfma32(pa0.v, vf[0][0], acc0);
    acc0 = mfma32(pa1.v, vf[1][0], acc0);
    acc1 = mfma32(pa0.v, vf[0][1], acc1);
    acc1 = mfma32(pa1.v, vf[1][1], acc1);
    __builtin_amdgcn_s_setprio(0);
  }

  float lt = lsum + __shfl_xor(lsum, 32);
  float inv = 1.0f / lt;
  #pragma unroll
  for (int r = 0; r < 16; ++r) {
    int rp = (r & 3) + 8 * (r >> 2) + 4 * hi;
    int idx = (((r & 3) + 8 * (r >> 2)) << 2) + (hi << 4);
    float ir = __int_as_float(__builtin_amdgcn_ds_bpermute(idx, __float_as_int(inv)));
    u16* orow = ctxb + (size_t)(q0 + rp) * D_MODEL;
    orow[lo] = f2bf(acc0[r] * ir);
    orow[32 + lo] = f2bf(acc1[r] * ir);
  }
}

__global__ __launch_bounds__(64) void attn_kernel(const u16* __restrict__ Q,
                                                  const u16* __restrict__ K,
                                                  const u16* __restrict__ Vt,
                                                  u16* __restrict__ ctx) {
  __shared__ alignas(128) char lds[16384];  // 2 bufs x (4KB K + 4KB V)
  const int lane = threadIdx.x;
  const int bid = blockIdx.x;          // 0..2047, XCD = bid%8 (perf heuristic)
  const int j = bid >> 3;              // 0..255
  const int bh = ((bid & 7) << 2) | (j >> 6);  // 4 heads per XCD group
  const int strip = 63 - (j & 63);     // longest strips dispatch first
  const u16* Qb = Q + (size_t)bh * SSEQ * DKH;
  const u16* Kb = K + (size_t)bh * SSEQ * DKH;
  const u16* Vb = Vt + (size_t)bh * DKH * SSEQ;
  u16* ctxb = ctx + (size_t)(bh >> 4) * SSEQ * D_MODEL + (bh & 15) * DKH;
  attn_strip32(Qb, Kb, Vb, ctxb, lds, strip, lane);
}

extern "C" void kernel_launch(void* const* d_in, const int* in_sizes, int n_in,
                              void* d_out, int out_size, void* d_ws, size_t ws_size,
                              hipStream_t stream) {
  const float* q  = (const float*)d_in[0];
  const float* k  = (const float*)d_in[1];
  const float* v  = (const float*)d_in[2];
  const float* Wq = (const float*)d_in[4];
  const float* bq = (const float*)d_in[5];
  const float* Wk = (const float*)d_in[6];
  const float* bk = (const float*)d_in[7];
  const float* Wv = (const float*)d_in[8];
  const float* bv = (const float*)d_in[9];
  const float* Wo = (const float*)d_in[10];
  const float* bo = (const float*)d_in[11];

  char* ws = (char*)d_ws;
  const size_t SZ_QKV = (size_t)NB * SSEQ * D_MODEL * 2;
  const size_t SZ_W   = (size_t)D_MODEL * D_MODEL * 2;
  u16* qb  = (u16*)(ws);
  u16* kb  = (u16*)(ws + SZ_QKV);
  u16* vb  = (u16*)(ws + 2 * SZ_QKV);
  u16* wqb = (u16*)(ws + 3 * SZ_QKV);
  u16* wkb = (u16*)(ws + 3 * SZ_QKV + SZ_W);
  u16* wvb = (u16*)(ws + 3 * SZ_QKV + 2 * SZ_W);
  u16* wob = (u16*)(ws + 3 * SZ_QKV + 3 * SZ_W);
  u16* Qh  = (u16*)(ws + 3 * SZ_QKV + 4 * SZ_W);
  u16* Kh  = (u16*)(ws + 4 * SZ_QKV + 4 * SZ_W);
  u16* Vh  = (u16*)(ws + 5 * SZ_QKV + 4 * SZ_W);
  u16* Vth = (u16*)(ws + 6 * SZ_QKV + 4 * SZ_W);
  u16* ctx = (u16*)(ws + 7 * SZ_QKV + 4 * SZ_W);

  cast_kernel<<<dim3(2048, 1, 3), 256, 0, stream>>>(
      q, k, v, nullptr, qb, kb, vb, nullptr, (NB * SSEQ * D_MODEL) / 8);
  cast_kernel<<<dim3(512, 1, 4), 256, 0, stream>>>(
      Wq, Wk, Wv, Wo, wqb, wkb, wvb, wob, (D_MODEL * D_MODEL) / 8);
  gemm_qkv<<<dim3(8, 32, 3), 256, 0, stream>>>(qb, kb, vb, wqb, wkb, wvb,
                                               bq, bk, bv, Qh, Kh, Vh);
  transpose_v<<<dim3(SSEQ / 64, NB * NHEAD), 256, 0, stream>>>(Vh, Vth);
  attn_kernel<<<dim3(2048), 64, 0, stream>>>(Qh, Kh, Vth, ctx);
  gemm_out<<<dim3(8, 32), 256, 0, stream>>>(ctx, wob, bo, (float*)d_out);
}